// Round 7
// baseline (1060.043 us; speedup 1.0000x reference)
//
#include <hip/hip_runtime.h>
#include <math.h>

#define TB 256

__device__ __forceinline__ float fast_sigmoid(float x) {
    return 1.0f / (1.0f + __expf(-x));
}
__device__ __forceinline__ float fast_tanh(float x) {
    float a = fabsf(x);
    float e = __expf(2.0f * a);
    float r = 1.0f - 2.0f / (e + 1.0f);
    return copysignf(r, x);
}
__device__ __forceinline__ float gelu_exact(float x) {
    return 0.5f * x * (1.0f + erff(x * 0.70710678118654752f));
}

// Workspace layout (floats):
//   [0)        slots_traj : 64512*128 = 8,257,536
//   [+)        state      : 512*128   = 65,536
//   [+)        A12g       : 4224
//   [+)        kqv        : 512*C*2048 (C = steps per segment, adaptive)
#define SLOTS_N  8257536ull
#define STATE_OFF SLOTS_N
#define A12_OFF  (SLOTS_N + 65536ull)
#define KQV_OFF  (A12_OFF + 4224ull)

// ---------------------------------------------------------------------------
// K0: fused-weight setup (1 block). Writes A12 (4096, [c][col] stride 128)
// and c12 (128) to ws.  (verified algebra, rounds 2-6)
//   Mkq[d][dp] = sum_e k_w[e][d] q_w[e][dp]
//   MvW[d][e]  = sum_e' v_w[e'][d] wih[e][e']
//   A12[c][col] = sum_d wts[d][c] * (col<32 ? Mkq[d][col] : MvW[d][col-32])
//   c12[col]    = sum_d bts[d]   * (same)
// ---------------------------------------------------------------------------
__global__ __launch_bounds__(256, 1) void setup_fused(
    const float* __restrict__ to_slot_w, const float* __restrict__ to_slot_b,
    const float* __restrict__ q_w, const float* __restrict__ k_w,
    const float* __restrict__ v_w, const float* __restrict__ wih,
    float* __restrict__ A12g)
{
    const int tid = threadIdx.x;
    __shared__ float wih_s[3072], vkq_s[3072], wts_s[1024];
    __shared__ float mkq_s[1024], mvw_s[3072];

    for (int i = tid; i < 3072; i += 256) wih_s[i] = wih[i];
    for (int i = tid; i < 1024; i += 256) {
        vkq_s[i]        = v_w[i];
        vkq_s[1024 + i] = k_w[i];
        vkq_s[2048 + i] = q_w[i];
        wts_s[i]        = to_slot_w[i];
    }
    __syncthreads();
    for (int o = tid; o < 1024; o += 256) {
        int d = o >> 5, dp = o & 31;
        float acc = 0.f;
#pragma unroll 8
        for (int e = 0; e < 32; ++e)
            acc += vkq_s[1024 + e * 32 + d] * vkq_s[2048 + e * 32 + dp];
        mkq_s[o] = acc;
    }
    for (int o = tid; o < 3072; o += 256) {
        int d = o / 96, e = o - d * 96;
        float acc = 0.f;
#pragma unroll 8
        for (int ep = 0; ep < 32; ++ep)
            acc += vkq_s[ep * 32 + d] * wih_s[e * 32 + ep];
        mvw_s[d * 96 + e] = acc;
    }
    __syncthreads();
    for (int o = tid; o < 4096; o += 256) {
        int c = o >> 7, col = o & 127;
        float acc = 0.f;
        if (col < 32) {
#pragma unroll 8
            for (int d = 0; d < 32; ++d) acc += wts_s[d * 32 + c] * mkq_s[d * 32 + col];
        } else {
            int e = col - 32;
#pragma unroll 8
            for (int d = 0; d < 32; ++d) acc += wts_s[d * 32 + c] * mvw_s[d * 96 + e];
        }
        A12g[o] = acc;
    }
    if (tid < 128) {
        int col = tid;
        float acc = 0.f;
        if (col < 32) {
            for (int d = 0; d < 32; ++d) acc += to_slot_b[d] * mkq_s[d * 32 + col];
        } else {
            int e = col - 32;
            for (int d = 0; d < 32; ++d) acc += to_slot_b[d] * mvw_s[d * 96 + e];
        }
        A12g[4096 + col] = acc;
    }
}

// ---------------------------------------------------------------------------
// P: precompute kq/vWT for one segment [t0, t0+Cs). 8 (b,t) pairs per block.
// m_local = b*Cs + tloc (segment-local). Per pair: feat = gelu(conv(X));
// [kq | vWT] = feat@A12 + c12.
// Output: kqv[m*2048 + n*32 + d]      (kq, n<16, d<32)
//         kqv[m*2048 + 512 + e*16 + n] (vWT, e<96, n<16)
// ---------------------------------------------------------------------------
__global__ __launch_bounds__(256, 2) void precompute_kqv(
    const float* __restrict__ frames, const float* __restrict__ conv_w,
    const float* __restrict__ conv_b, const float* __restrict__ A12g,
    float* __restrict__ kqv, int t0, int Cs)
{
    const int tid = threadIdx.x;
    const int m0 = blockIdx.x * 8;

    __shared__ float A12_s[4224];
    __shared__ float X_s[8][16 * 36];
    __shared__ float feat_s[8][16 * 36];

    for (int i = tid; i < 4224; i += 256) A12_s[i] = A12g[i];

    // load frames -> X (32 threads per pair, 4 float4 each)
    {
        int pair = tid >> 5, fq = tid & 31;
        int m = m0 + pair;
        int bb = m / Cs, tl = m - bb * Cs;
        const float* base = frames + (size_t)bb * 32768 + (size_t)(t0 + tl) * 256;
#pragma unroll
        for (int k = 0; k < 4; ++k) {
            int f = fq + 32 * k;
            int h = f >> 6, rem = f & 63;
            int i = rem >> 2, j4 = rem & 3;
            // h=0: curr = frame t+1 ; h=1: prev = frame t
            float4 v = *(const float4*)&base[(h ? 0 : 256) + i * 16 + j4 * 4];
            int n = (i >> 2) * 4 + j4, pr = i & 3;
            *(float4*)&X_s[pair][n * 36 + h * 16 + pr * 4] = v;
        }
    }
    // conv weight row in regs
    const int o = tid & 31, g = tid >> 5;
    float cw[32];
    {
        const float* wp = conv_w + o * 32;
#pragma unroll
        for (int k = 0; k < 32; k += 4) {
            float4 v = *(const float4*)&wp[k];
            cw[k] = v.x; cw[k + 1] = v.y; cw[k + 2] = v.z; cw[k + 3] = v.w;
        }
    }
    const float cb = conv_b[o];
    __syncthreads();

    // conv + gelu: thread (o, pair=g) computes 16 n's
    {
        int pair = g;
#pragma unroll
        for (int n = 0; n < 16; ++n) {
            const float* xr = &X_s[pair][n * 36];
            float acc = cb;
#pragma unroll
            for (int k = 0; k < 32; k += 4) {
                float4 x4 = *(const float4*)&xr[k];
                acc += cw[k] * x4.x + cw[k + 1] * x4.y + cw[k + 2] * x4.z + cw[k + 3] * x4.w;
            }
            feat_s[pair][n * 36 + o] = gelu_exact(acc);
        }
    }
    __syncthreads();

    // KQV GEMM: thread = (c0 = 2*(tid&63), pg = tid>>6); pairs pg*2, pg*2+1
    const int c0 = 2 * (tid & 63);
    const int pg = tid >> 6;
    const float cx = A12_s[4096 + c0], cy = A12_s[4096 + c0 + 1];

#pragma unroll
    for (int pp = 0; pp < 2; ++pp) {
        int pair = pg * 2 + pp;
        float accx[16], accy[16];
#pragma unroll
        for (int n = 0; n < 16; ++n) { accx[n] = 0.f; accy[n] = 0.f; }
#pragma unroll
        for (int c4 = 0; c4 < 8; ++c4) {
            float2 a0 = *(const float2*)&A12_s[(c4 * 4 + 0) * 128 + c0];
            float2 a1 = *(const float2*)&A12_s[(c4 * 4 + 1) * 128 + c0];
            float2 a2 = *(const float2*)&A12_s[(c4 * 4 + 2) * 128 + c0];
            float2 a3 = *(const float2*)&A12_s[(c4 * 4 + 3) * 128 + c0];
#pragma unroll
            for (int n = 0; n < 16; ++n) {
                float4 f = *(const float4*)&feat_s[pair][n * 36 + c4 * 4];
                accx[n] += f.x * a0.x + f.y * a1.x + f.z * a2.x + f.w * a3.x;
                accy[n] += f.x * a0.y + f.y * a1.y + f.z * a2.y + f.w * a3.y;
            }
        }
        float* outp = kqv + (size_t)(m0 + pair) * 2048;
        if (c0 < 32) {
#pragma unroll
            for (int n = 0; n < 16; ++n)
                *(float2*)&outp[n * 32 + c0] = make_float2(accx[n] + cx, accy[n] + cy);
        } else {
            int e0 = c0 - 32;
#pragma unroll
            for (int n4 = 0; n4 < 4; ++n4) {
                *(float4*)&outp[512 + e0 * 16 + n4 * 4] =
                    make_float4(accx[n4 * 4] + cx, accx[n4 * 4 + 1] + cx,
                                accx[n4 * 4 + 2] + cx, accx[n4 * 4 + 3] + cx);
                *(float4*)&outp[512 + (e0 + 1) * 16 + n4 * 4] =
                    make_float4(accy[n4 * 4] + cy, accy[n4 * 4 + 1] + cy,
                                accy[n4 * 4 + 2] + cy, accy[n4 * 4 + 3] + cy);
            }
        }
    }
}

// ---------------------------------------------------------------------------
// S: cooperative sequential kernel for one segment. 512 blocks x 256 thr.
// Register-resident operands: whh rows (persistent, global->reg, NO LDS),
// kq row + 3 vWT rows (per step, reused x3 iters). Per iter: 2 barriers.
// Phase A: wave0 logits+shfl-softmax -> attn_s ; waves1-3 gh -> gh_s.
// Phase B: 128 thr gi (reg vWT) + GRU combine -> slots_s (+traj at it2);
//          stage next step's kqv (regs -> LDS) at it2.
// ---------------------------------------------------------------------------
__global__ __launch_bounds__(256, 2) void slot_seq2(
    const float* __restrict__ kqv, const float* __restrict__ slot_mu,
    const float* __restrict__ whh, const float* __restrict__ bih,
    const float* __restrict__ bhh, float* __restrict__ state,
    float* __restrict__ slots_traj, int t0, int Cs)
{
    const int tid = threadIdx.x;
    const int b = blockIdx.x;
    const int lane = tid & 63;
    const int wid = tid >> 6;

    __shared__ float kq_s[16 * 36];    // [n][d]
    __shared__ float vwt_s[96 * 20];   // [e][n]
    __shared__ float slots_s[4 * 36];  // [s][d]
    __shared__ float attn_s[4 * 20];   // [s][n]
    __shared__ float gh_s[4 * 100];    // [s][e]

    const int s_l = lane >> 4, n_l = lane & 15;  // wave0 logits map
    const int sB = tid >> 5, dB = tid & 31;      // phase-B map (tid<128)

    // persistent registers
    int sh = 0, e3 = 0;
    float4 wh4[8];
    float bh = 0.f;
    if (wid > 0) {
        int idx3 = tid - 64;
        sh = idx3 / 96;
        e3 = idx3 - sh * 96;
#pragma unroll
        for (int c = 0; c < 8; ++c)
            wh4[c] = *(const float4*)&whh[e3 * 32 + 4 * c];
        bh = bhh[e3];
    }
    float bi0 = 0.f, bi1 = 0.f, bi2 = 0.f;
    if (tid < 128) {
        bi0 = bih[dB]; bi1 = bih[dB + 32]; bi2 = bih[dB + 64];
        float v = (t0 == 0) ? slot_mu[sB * 32 + dB] : state[b * 128 + sB * 32 + dB];
        slots_s[sB * 36 + dB] = v;
    }

    const float* kb = kqv + (size_t)b * Cs * 2048;
    // stage step 0 (global -> LDS)
    {
        float4 v0 = *(const float4*)&kb[4 * tid];
        float4 v1 = *(const float4*)&kb[1024 + 4 * tid];
        int f0 = 4 * tid;
        if (f0 < 512) { int n = f0 >> 5, d = f0 & 31; *(float4*)&kq_s[n * 36 + d] = v0; }
        else          { int q = f0 - 512; *(float4*)&vwt_s[(q >> 4) * 20 + (q & 15)] = v0; }
        { int q = f0 + 512; *(float4*)&vwt_s[(q >> 4) * 20 + (q & 15)] = v1; }
    }
    __syncthreads();

    float4 pf0 = make_float4(0, 0, 0, 0), pf1 = pf0;

#pragma unroll 1
    for (int tloc = 0; tloc < Cs; ++tloc) {
        // prefetch next step into regs (lands during 3 iterations)
        if (tloc + 1 < Cs) {
            const float* src = kb + (size_t)(tloc + 1) * 2048;
            pf0 = *(const float4*)&src[4 * tid];
            pf1 = *(const float4*)&src[1024 + 4 * tid];
        }
        // per-step consumer loads: LDS -> regs (reused over 3 iterations)
        float4 kr4[8];
        if (wid == 0) {
#pragma unroll
            for (int c = 0; c < 8; ++c)
                kr4[c] = *(const float4*)&kq_s[n_l * 36 + 4 * c];
        }
        float4 vr0[4], vr1[4], vr2[4];
        if (tid < 128) {
#pragma unroll
            for (int c = 0; c < 4; ++c) {
                vr0[c] = *(const float4*)&vwt_s[dB * 20 + 4 * c];
                vr1[c] = *(const float4*)&vwt_s[(dB + 32) * 20 + 4 * c];
                vr2[c] = *(const float4*)&vwt_s[(dB + 64) * 20 + 4 * c];
            }
        }

#pragma unroll 1
        for (int it = 0; it < 3; ++it) {
            // ---- phase A ----
            if (wid == 0) {
                const float* sp = &slots_s[s_l * 36];
                float acc = 0.f;
#pragma unroll
                for (int c = 0; c < 8; ++c) {
                    float4 s4 = *(const float4*)&sp[4 * c];
                    acc += kr4[c].x * s4.x + kr4[c].y * s4.y + kr4[c].z * s4.z + kr4[c].w * s4.w;
                }
                float lg = acc * 0.17677669529663687f;  // 1/sqrt(32)
                float m = fmaxf(lg, __shfl_xor(lg, 16));
                m = fmaxf(m, __shfl_xor(m, 32));
                float e = __expf(lg - m);
                float ss = e + __shfl_xor(e, 16);
                ss += __shfl_xor(ss, 32);
                attn_s[s_l * 20 + n_l] = e / ss;
            } else {
                int s0 = sh * 2;
                const float* sa = &slots_s[s0 * 36];
                const float* sb2 = &slots_s[(s0 + 1) * 36];
                float acc0 = bh, acc1 = bh;
#pragma unroll
                for (int c = 0; c < 8; ++c) {
                    float4 a4 = *(const float4*)&sa[4 * c];
                    float4 b4 = *(const float4*)&sb2[4 * c];
                    acc0 += wh4[c].x * a4.x + wh4[c].y * a4.y + wh4[c].z * a4.z + wh4[c].w * a4.w;
                    acc1 += wh4[c].x * b4.x + wh4[c].y * b4.y + wh4[c].z * b4.z + wh4[c].w * b4.w;
                }
                gh_s[s0 * 100 + e3] = acc0;
                gh_s[(s0 + 1) * 100 + e3] = acc1;
            }
            __syncthreads();
            // ---- phase B ----
            if (tid < 128) {
                float gir = bi0, giz = bi1, gin = bi2;
#pragma unroll
                for (int c = 0; c < 4; ++c) {
                    float4 a4 = *(const float4*)&attn_s[sB * 20 + 4 * c];
                    gir += a4.x * vr0[c].x + a4.y * vr0[c].y + a4.z * vr0[c].z + a4.w * vr0[c].w;
                    giz += a4.x * vr1[c].x + a4.y * vr1[c].y + a4.z * vr1[c].z + a4.w * vr1[c].w;
                    gin += a4.x * vr2[c].x + a4.y * vr2[c].y + a4.z * vr2[c].z + a4.w * vr2[c].w;
                }
                float ghr = gh_s[sB * 100 + dB];
                float ghz = gh_s[sB * 100 + 32 + dB];
                float ghn = gh_s[sB * 100 + 64 + dB];
                float r = fast_sigmoid(gir + ghr);
                float z = fast_sigmoid(giz + ghz);
                float nn = fast_tanh(gin + r * ghn);
                float h = slots_s[sB * 36 + dB];
                float hn = (1.f - z) * nn + z * h;
                slots_s[sB * 36 + dB] = hn;
                if (it == 2)
                    slots_traj[((size_t)b * 126 + t0 + tloc) * 128 + sB * 32 + dB] = hn;
            }
            if (it == 2 && tloc + 1 < Cs) {
                // stage prefetched step (regs -> LDS); consumers already hold
                // this step's data in regs, so single-buffer is race-free.
                int f0 = 4 * tid;
                if (f0 < 512) { int n = f0 >> 5, d = f0 & 31; *(float4*)&kq_s[n * 36 + d] = pf0; }
                else          { int q = f0 - 512; *(float4*)&vwt_s[(q >> 4) * 20 + (q & 15)] = pf0; }
                { int q = f0 + 512; *(float4*)&vwt_s[(q >> 4) * 20 + (q & 15)] = pf1; }
            }
            __syncthreads();
        }
    }
    if (tid < 128)
        state[b * 128 + sB * 32 + dB] = slots_s[sB * 36 + dB];
}

// ---------------------------------------------------------------------------
// FALLBACK kernel A (round-2 structure, verified 809 us): used when ws_size
// is too small for the precompute path.
// ---------------------------------------------------------------------------
__global__ __launch_bounds__(256, 2) void slot_recur_kernel(
    const float* __restrict__ frames, const float* __restrict__ slot_mu,
    const float* __restrict__ conv_w, const float* __restrict__ conv_b,
    const float* __restrict__ to_slot_w, const float* __restrict__ to_slot_b,
    const float* __restrict__ q_w, const float* __restrict__ k_w,
    const float* __restrict__ v_w,
    const float* __restrict__ wih, const float* __restrict__ whh,
    const float* __restrict__ bih, const float* __restrict__ bhh,
    float* __restrict__ slots_out)
{
    const int tid = threadIdx.x;
    const int b = blockIdx.x;
    const int lane = tid & 63;
    const int wid = tid >> 6;

    __shared__ float A12_s[32 * 132];
    __shared__ float c12_s[128];
    __shared__ float whh_s[96 * 36];
    __shared__ float vWT_s[96 * 20];
    __shared__ float kq_s[16 * 36];
    __shared__ float X_s[16 * 36];
    __shared__ float feat_s[16 * 36];
    __shared__ float slots_s[4 * 36];
    __shared__ float attn_s[4 * 20];
    __shared__ float bih_s[96], bhh_s[96];
    __shared__ float Mkq_s[1024];
    __shared__ float scr_s[32 * 96];
    __shared__ float gh_s[4 * 100], gi_s[4 * 100];

    for (int i = tid; i < 3072; i += 256) A12_s[i] = wih[i];
    for (int i = tid; i < 1024; i += 256) {
        whh_s[i]        = v_w[i];
        whh_s[1024 + i] = k_w[i];
        whh_s[2048 + i] = q_w[i];
        vWT_s[i]        = to_slot_w[i];
    }
    __syncthreads();
    for (int o = tid; o < 1024; o += 256) {
        int d = o >> 5, dp = o & 31;
        float acc = 0.f;
#pragma unroll 8
        for (int e = 0; e < 32; ++e)
            acc += whh_s[1024 + e * 32 + d] * whh_s[2048 + e * 32 + dp];
        Mkq_s[o] = acc;
    }
    for (int o = tid; o < 3072; o += 256) {
        int d = o / 96, e = o - d * 96;
        float acc = 0.f;
#pragma unroll 8
        for (int ep = 0; ep < 32; ++ep)
            acc += whh_s[ep * 32 + d] * A12_s[e * 32 + ep];
        scr_s[d * 96 + e] = acc;
    }
    __syncthreads();
    for (int o = tid; o < 4096; o += 256) {
        int c = o >> 7, col = o & 127;
        float acc = 0.f;
        if (col < 32) {
#pragma unroll 8
            for (int d = 0; d < 32; ++d) acc += vWT_s[d * 32 + c] * Mkq_s[d * 32 + col];
        } else {
            int e = col - 32;
#pragma unroll 8
            for (int d = 0; d < 32; ++d) acc += vWT_s[d * 32 + c] * scr_s[d * 96 + e];
        }
        A12_s[c * 132 + col] = acc;
    }
    if (tid < 128) {
        int col = tid;
        float acc = 0.f;
        if (col < 32) {
            for (int d = 0; d < 32; ++d) acc += to_slot_b[d] * Mkq_s[d * 32 + col];
        } else {
            int e = col - 32;
            for (int d = 0; d < 32; ++d) acc += to_slot_b[d] * scr_s[d * 96 + e];
        }
        c12_s[col] = acc;
    }
    for (int i = tid; i < 3072; i += 256) whh_s[(i >> 5) * 36 + (i & 31)] = whh[i];
    if (tid < 96) { bih_s[tid] = bih[tid]; bhh_s[tid] = bhh[tid]; }
    if (tid < 128) slots_s[(tid >> 5) * 36 + (tid & 31)] = slot_mu[tid];

    const float* fb = frames + (size_t)b * (128 * 256);
    if (tid < 128) {
        int h = tid >> 6, ll = tid & 63;
        int i = ll >> 2, j4 = ll & 3;
        float4 v = *(const float4*)&fb[(h ? 0 : 256) + i * 16 + j4 * 4];
        int n = (i >> 2) * 4 + j4, p = i & 3;
        *(float4*)&X_s[n * 36 + h * 16 + p * 4] = v;
    }
    __syncthreads();

    float* so = slots_out + (size_t)b * (126 * 128);

#pragma unroll 1
    for (int t = 0; t < 126; ++t) {
        {
            int o = tid & 31, ng = tid >> 5;
            const float* w = conv_w + o * 32;
            float acca = conv_b[o], accb = acca;
            const float* xa = &X_s[ng * 36];
            const float* xb = &X_s[(ng + 8) * 36];
#pragma unroll
            for (int k = 0; k < 32; k += 4) {
                float4 w4 = *(const float4*)&w[k];
                float4 a4 = *(const float4*)&xa[k];
                float4 b4 = *(const float4*)&xb[k];
                acca += w4.x * a4.x + w4.y * a4.y + w4.z * a4.z + w4.w * a4.w;
                accb += w4.x * b4.x + w4.y * b4.y + w4.z * b4.z + w4.w * b4.w;
            }
            feat_s[ng * 36 + o] = gelu_exact(acca);
            feat_s[(ng + 8) * 36 + o] = gelu_exact(accb);
        }
        __syncthreads();

        float4 pf;
        const bool havepf = (t < 125) && (tid < 128);
        if (havepf) {
            int h = tid >> 6, ll = tid & 63;
            int i = ll >> 2, j4 = ll & 3;
            pf = *(const float4*)&fb[(t + (h ? 1 : 2)) * 256 + i * 16 + j4 * 4];
        }
        {
            const int cg = tid & 63;
            const int wv = tid >> 6;
            const int col0 = cg * 2;
            float accx[4], accy[4];
#pragma unroll
            for (int j = 0; j < 4; ++j) { accx[j] = 0.f; accy[j] = 0.f; }
#pragma unroll
            for (int c = 0; c < 32; c += 4) {
                float2 a0 = *(const float2*)&A12_s[(c + 0) * 132 + col0];
                float2 a1 = *(const float2*)&A12_s[(c + 1) * 132 + col0];
                float2 a2 = *(const float2*)&A12_s[(c + 2) * 132 + col0];
                float2 a3 = *(const float2*)&A12_s[(c + 3) * 132 + col0];
#pragma unroll
                for (int j = 0; j < 4; ++j) {
                    float4 q = *(const float4*)&feat_s[(wv * 4 + j) * 36 + c];
                    accx[j] += a0.x * q.x + a1.x * q.y + a2.x * q.z + a3.x * q.w;
                    accy[j] += a0.y * q.x + a1.y * q.y + a2.y * q.z + a3.y * q.w;
                }
            }
            float cx = c12_s[col0], cy = c12_s[col0 + 1];
#pragma unroll
            for (int j = 0; j < 4; ++j) {
                int n = wv * 4 + j;
                float vx = accx[j] + cx, vy = accy[j] + cy;
                if (col0 < 32) {
                    *(float2*)&kq_s[n * 36 + col0] = make_float2(vx, vy);
                } else {
                    vWT_s[(col0 - 32) * 20 + n] = vx;
                    vWT_s[(col0 - 31) * 20 + n] = vy;
                }
            }
        }
        if (havepf) {
            int h = tid >> 6, ll = tid & 63;
            int i = ll >> 2, j4 = ll & 3;
            int n = (i >> 2) * 4 + j4, p = i & 3;
            *(float4*)&X_s[n * 36 + h * 16 + p * 4] = pf;
        }
        __syncthreads();

#pragma unroll 1
        for (int it = 0; it < 3; ++it) {
            if (wid == 0) {
                int s = lane >> 4, n = lane & 15;
                const float* sp = &slots_s[s * 36];
                const float* kp = &kq_s[n * 36];
                float acc = 0.f;
#pragma unroll
                for (int d = 0; d < 32; d += 4) {
                    float4 a = *(const float4*)&sp[d];
                    float4 c = *(const float4*)&kp[d];
                    acc += a.x * c.x + a.y * c.y + a.z * c.z + a.w * c.w;
                }
                float lg = acc * 0.17677669529663687f;
                float m = fmaxf(lg, __shfl_xor(lg, 16));
                m = fmaxf(m, __shfl_xor(m, 32));
                float e = __expf(lg - m);
                float ssum = e + __shfl_xor(e, 16);
                ssum += __shfl_xor(ssum, 32);
                attn_s[s * 20 + n] = e / ssum;
            } else {
                int idx = tid - 64;
                int shh = idx / 96;
                int e = idx - shh * 96;
                int s0 = shh * 2;
                const float* w = &whh_s[e * 36];
                const float* sa = &slots_s[s0 * 36];
                const float* sb = &slots_s[(s0 + 1) * 36];
                float acc0 = bhh_s[e], acc1 = acc0;
#pragma unroll
                for (int d = 0; d < 32; d += 4) {
                    float4 w4 = *(const float4*)&w[d];
                    float4 a4 = *(const float4*)&sa[d];
                    float4 b4 = *(const float4*)&sb[d];
                    acc0 += w4.x * a4.x + w4.y * a4.y + w4.z * a4.z + w4.w * a4.w;
                    acc1 += w4.x * b4.x + w4.y * b4.y + w4.z * b4.z + w4.w * b4.w;
                }
                gh_s[s0 * 100 + e] = acc0;
                gh_s[(s0 + 1) * 100 + e] = acc1;
            }
            __syncthreads();
            if (tid < 192) {
                int shh = tid / 96;
                int e = tid - shh * 96;
                int s0 = shh * 2;
                const float* vp = &vWT_s[e * 20];
                const float* a0 = &attn_s[s0 * 20];
                const float* a1 = &attn_s[(s0 + 1) * 20];
                float g0 = bih_s[e], g1 = g0;
#pragma unroll
                for (int n = 0; n < 16; n += 4) {
                    float4 v4 = *(const float4*)&vp[n];
                    float4 x0 = *(const float4*)&a0[n];
                    float4 x1 = *(const float4*)&a1[n];
                    g0 += v4.x * x0.x + v4.y * x0.y + v4.z * x0.z + v4.w * x0.w;
                    g1 += v4.x * x1.x + v4.y * x1.y + v4.z * x1.z + v4.w * x1.w;
                }
                gi_s[s0 * 100 + e] = g0;
                gi_s[(s0 + 1) * 100 + e] = g1;
            }
            __syncthreads();
            if (tid < 128) {
                int s = tid >> 5, d = tid & 31;
                float gir = gi_s[s * 100 + d],      ghr = gh_s[s * 100 + d];
                float giz = gi_s[s * 100 + 32 + d], ghz = gh_s[s * 100 + 32 + d];
                float gin = gi_s[s * 100 + 64 + d], ghn = gh_s[s * 100 + 64 + d];
                float r = fast_sigmoid(gir + ghr);
                float z = fast_sigmoid(giz + ghz);
                float nn = fast_tanh(gin + r * ghn);
                float h = slots_s[s * 36 + d];
                float hn = (1.0f - z) * nn + z * h;
                slots_s[s * 36 + d] = hn;
                if (it == 2) so[t * 128 + tid] = hn;
            }
            __syncthreads();
        }
    }
}

// ---------------------------------------------------------------------------
// Kernel B: batched decode (unchanged, verified).
// ---------------------------------------------------------------------------
__global__ __launch_bounds__(TB, 1) void decode_kernel(
    const float* __restrict__ slots_traj, const float* __restrict__ frames,
    const float* __restrict__ dec_w, const float* __restrict__ dec_b,
    const float* __restrict__ deconv_w, const float* __restrict__ deconv_b,
    float* __restrict__ out)
{
    const int tid = threadIdx.x;
    const int m0 = blockIdx.x * 32;

    __shared__ float sl_s[32 * 132];
    __shared__ float wch_s[64 * 132];
    __shared__ float dw_s[512];
    __shared__ float db_s[512];

    for (int i = tid * 4; i < 32 * 128; i += TB * 4) {
        float4 v = *(const float4*)&slots_traj[(size_t)m0 * 128 + i];
        int r = i >> 7, k = i & 127;
        *(float4*)&sl_s[r * 132 + k] = v;
    }
    for (int i = tid; i < 512; i += TB) {
        dw_s[i] = deconv_w[i];
        db_s[i] = dec_b[i];
    }
    __syncthreads();

    const int cg = tid & 63;
    const int rg = tid >> 6;

    float acc[8][8];
#pragma unroll
    for (int ci = 0; ci < 8; ++ci)
#pragma unroll
        for (int rr = 0; rr < 8; ++rr) acc[ci][rr] = 0.f;

    const float* slb = &sl_s[(rg * 8) * 132];

#pragma unroll
    for (int ch = 0; ch < 8; ++ch) {
        for (int i = tid * 4; i < 64 * 128; i += TB * 4) {
            float4 v = *(const float4*)&dec_w[(size_t)ch * 8192 + i];
            int cl = i >> 7, k = i & 127;
            *(float4*)&wch_s[cl * 132 + k] = v;
        }
        __syncthreads();
        const float* wrow = &wch_s[cg * 132];
#pragma unroll 4
        for (int k = 0; k < 128; k += 4) {
            float4 w4 = *(const float4*)&wrow[k];
#pragma unroll
            for (int rr = 0; rr < 8; ++rr) {
                float4 s4 = *(const float4*)&slb[rr * 132 + k];
                acc[ch][rr] += w4.x * s4.x + w4.y * s4.y + w4.z * s4.z + w4.w * s4.w;
            }
        }
        __syncthreads();
    }

#pragma unroll
    for (int ci = 0; ci < 8; ++ci) {
        float bo = db_s[cg + 64 * ci];
#pragma unroll
        for (int rr = 0; rr < 8; ++rr) acc[ci][rr] += bo;
    }

    const int c0 = cg >> 4;
    const int sp = cg & 15;
    const int bi = sp >> 2, bj = sp & 3;
    const float db0 = deconv_b[0];

#pragma unroll 1
    for (int rr = 0; rr < 8; ++rr) {
        float part[16];
#pragma unroll
        for (int kl = 0; kl < 16; ++kl) part[kl] = 0.f;
#pragma unroll
        for (int m = 0; m < 8; ++m) {
            float sf = acc[m][rr];
            const float* dwp = &dw_s[(c0 + 4 * m) * 16];
#pragma unroll
            for (int kl = 0; kl < 16; ++kl) part[kl] += sf * dwp[kl];
        }
#pragma unroll
        for (int kl = 0; kl < 16; ++kl) {
            part[kl] += __shfl_xor(part[kl], 16);
            part[kl] += __shfl_xor(part[kl], 32);
        }
        if (c0 == 0) {
            int mrow = m0 + rg * 8 + rr;
            int bb = mrow / 126, tt = mrow - bb * 126;
            const float* fr = frames + ((size_t)bb * 128 + (tt + 1)) * 256;
            float* op = out + (size_t)mrow * 256;
#pragma unroll
            for (int kk = 0; kk < 4; ++kk) {
                int pixb = (bi * 4 + kk) * 16 + bj * 4;
                float4 c4 = *(const float4*)&fr[pixb];
                float4 o4;
                o4.x = fminf(fmaxf(c4.x + tanhf(part[kk * 4 + 0] + db0), 0.f), 1.f);
                o4.y = fminf(fmaxf(c4.y + tanhf(part[kk * 4 + 1] + db0), 0.f), 1.f);
                o4.z = fminf(fmaxf(c4.z + tanhf(part[kk * 4 + 2] + db0), 0.f), 1.f);
                o4.w = fminf(fmaxf(c4.w + tanhf(part[kk * 4 + 3] + db0), 0.f), 1.f);
                *(float4*)&op[pixb] = o4;
            }
        }
    }
}

extern "C" void kernel_launch(void* const* d_in, const int* in_sizes, int n_in,
                              void* d_out, int out_size, void* d_ws, size_t ws_size,
                              hipStream_t stream) {
    const float* frames    = (const float*)d_in[0];
    const float* slot_mu   = (const float*)d_in[1];
    const float* conv_w    = (const float*)d_in[2];
    const float* conv_b    = (const float*)d_in[3];
    const float* to_slot_w = (const float*)d_in[4];
    const float* to_slot_b = (const float*)d_in[5];
    const float* q_w       = (const float*)d_in[6];
    const float* k_w       = (const float*)d_in[7];
    const float* v_w       = (const float*)d_in[8];
    const float* gru_wih   = (const float*)d_in[9];
    const float* gru_whh   = (const float*)d_in[10];
    const float* gru_bih   = (const float*)d_in[11];
    const float* gru_bhh   = (const float*)d_in[12];
    const float* dec_w     = (const float*)d_in[13];
    const float* dec_b     = (const float*)d_in[14];
    const float* deconv_w  = (const float*)d_in[15];
    const float* deconv_b  = (const float*)d_in[16];

    float* ws = (float*)d_ws;
    float* slots_traj = ws;
    float* state      = ws + STATE_OFF;
    float* A12g       = ws + A12_OFF;
    float* kqv        = ws + KQV_OFF;
    float* outp = (float*)d_out;

    size_t wsf = ws_size / 4;
    long cap = (wsf > KQV_OFF) ? (long)((wsf - KQV_OFF) / (512ull * 2048ull)) : 0;

    if (cap >= 6) {
        // segment count balanced: nseg = ceil(126/cap), C = ceil(126/nseg)
        long capc = cap < 126 ? cap : 126;
        int nseg = (int)((126 + capc - 1) / capc);
        int C = (126 + nseg - 1) / nseg;
        hipLaunchKernelGGL(setup_fused, dim3(1), dim3(256), 0, stream,
                           to_slot_w, to_slot_b, q_w, k_w, v_w, gru_wih, A12g);
        for (int t0 = 0; t0 < 126; t0 += C) {
            int Cs = (126 - t0 < C) ? (126 - t0) : C;
            hipLaunchKernelGGL(precompute_kqv, dim3(64 * Cs), dim3(256), 0, stream,
                               frames, conv_w, conv_b, A12g, kqv, t0, Cs);
            hipLaunchKernelGGL(slot_seq2, dim3(512), dim3(256), 0, stream,
                               kqv, slot_mu, gru_whh, gru_bih, gru_bhh,
                               state, slots_traj, t0, Cs);
        }
    } else {
        hipLaunchKernelGGL(slot_recur_kernel, dim3(512), dim3(256), 0, stream,
                           frames, slot_mu, conv_w, conv_b, to_slot_w, to_slot_b,
                           q_w, k_w, v_w, gru_wih, gru_whh, gru_bih, gru_bhh,
                           slots_traj);
    }
    hipLaunchKernelGGL(decode_kernel, dim3(64512 / 32), dim3(TB), 0, stream,
                       slots_traj, frames, dec_w, dec_b, deconv_w, deconv_b,
                       outp);
}